// Round 12
// baseline (272.237 us; speedup 1.0000x reference)
//
#include <hip/hip_runtime.h>

#define NN    100000
#define IND   512
#define HID   128
#define OUTD  64
#define NBUCK 782          // ceil(NN/128); bucket = dst >> 7
#define NB    256          // partition chunks
#define NGEMM 782          // (NN+127)/128 gemm tiles
#define GH1   392          // gemm tiles in partgemm launch
#define GH2   390          // gemm tiles in sortgemm launch
#define NPREP 64           // prep blocks appended to count launch

typedef _Float16 half8_t __attribute__((ext_vector_type(8)));
typedef _Float16 half4_t __attribute__((ext_vector_type(4)));
typedef float f32x4 __attribute__((ext_vector_type(4)));

// ---------------- count (blocks 0..NB-1) + prep (blocks NB..NB+NPREP-1) ----------------
__global__ __launch_bounds__(1024) void countprep_k(const int* __restrict__ dst,
                                                    int* __restrict__ counts, int nE, int CH,
                                                    const float* __restrict__ W1,
                                                    const float* __restrict__ W2,
                                                    _Float16* __restrict__ W1t,
                                                    _Float16* __restrict__ W2t) {
    __shared__ int bins[NBUCK];
    const int bid = blockIdx.x, tid = threadIdx.x;
    if (bid >= NB) {   // prep: W1t[c][k] = (f16)W1[k][c], W2t[c][k] = (f16)W2[k][c]
        int idx = (bid - NB) * 1024 + tid;
        if (idx < IND * HID) { int c = idx >> 9, k = idx & 511; W1t[idx] = (_Float16)W1[k * HID + c]; }
        if (idx < HID * OUTD) { int c = idx >> 7, k = idx & 127; W2t[idx] = (_Float16)W2[k * OUTD + c]; }
        return;
    }
    for (int b = tid; b < NBUCK; b += 1024) bins[b] = 0;
    __syncthreads();
    int lo = bid * CH, hi = min(lo + CH, nE);
    for (int e = lo + tid; e < hi; e += 1024) atomicAdd(&bins[dst[e] >> 7], 1);
    __syncthreads();
    for (int b = tid; b < NBUCK; b += 1024) counts[b * NB + bid] = bins[b];
}

__global__ __launch_bounds__(256) void bsum_k(const int* __restrict__ counts,
                                              int* __restrict__ bsum) {
    __shared__ int s[256];
    const int b = blockIdx.x, t = threadIdx.x;
    s[t] = counts[b * NB + t];
    __syncthreads();
    for (int off = 128; off > 0; off >>= 1) {
        if (t < off) s[t] += s[t + off];
        __syncthreads();
    }
    if (t == 0) bsum[b] = s[0];
}

__global__ __launch_bounds__(1024) void scan_top_k(const int* __restrict__ bsum,
                                                   int* __restrict__ bucketStart, int n) {
    __shared__ int s[1024];
    const int t = threadIdx.x;
    int v = (t < n) ? bsum[t] : 0;
    s[t] = v;
    __syncthreads();
    for (int off = 1; off < 1024; off <<= 1) {
        int x = (t >= off) ? s[t - off] : 0;
        __syncthreads();
        s[t] += x;
        __syncthreads();
    }
    if (t < n) bucketStart[t] = s[t] - v;
    if (t == n - 1) bucketStart[n] = s[t];
}

__global__ __launch_bounds__(256) void boff_k(int* __restrict__ counts,
                                              const int* __restrict__ bucketStart) {
    __shared__ int s[256];
    const int b = blockIdx.x, t = threadIdx.x;
    int v = counts[b * NB + t];
    s[t] = v;
    __syncthreads();
    for (int off = 1; off < 256; off <<= 1) {
        int x = (t >= off) ? s[t - off] : 0;
        __syncthreads();
        s[t] += x;
        __syncthreads();
    }
    counts[b * NB + t] = bucketStart[b] + s[t] - v;
}

// ---------------- shared gemm tile body: H2 = relu(F @ W1) @ W2, f16 MFMA ----------------
__device__ __forceinline__ void gemm_tile(int tile, const float* __restrict__ F,
                                          const _Float16* __restrict__ W1t,
                                          const _Float16* __restrict__ W2t,
                                          _Float16* __restrict__ H2,
                                          _Float16* smem, _Float16* W2s, int tid) {
    _Float16* At = smem;
    _Float16* Bt = smem + 128 * 64;
    const int wid  = tid >> 6;
    const int lane = tid & 63;
    const int l15  = lane & 15;
    const int l4   = lane >> 4;
    const int brow = tile * 128;

#pragma unroll
    for (int i = 0; i < 4; i++) {
        int idx = i * 256 + tid;
        int r = idx >> 4, sl = idx & 15;
        int u = (r * 128 + sl * 8) ^ ((r & 7) << 3);
        *(uint4*)(&W2s[u]) = *(const uint4*)(W2t + r * 128 + sl * 8);
    }

    f32x4 acc[2][8];
#pragma unroll
    for (int mt = 0; mt < 2; mt++)
#pragma unroll
        for (int nt = 0; nt < 8; nt++) acc[mt][nt] = (f32x4)0.f;

    for (int chunk = 0; chunk < 8; chunk++) {
        const int kc = chunk * 64;
#pragma unroll
        for (int i = 0; i < 8; i++) {
            int idx = i * 256 + tid;
            int r = idx >> 4, c4 = idx & 15;
            int gr = brow + r; if (gr >= NN) gr = NN - 1;
            float4 v = *(const float4*)(F + (size_t)gr * IND + kc + c4 * 4);
            half4_t h; h.x = (_Float16)v.x; h.y = (_Float16)v.y; h.z = (_Float16)v.z; h.w = (_Float16)v.w;
            int u = (r * 64 + c4 * 4) ^ ((r & 7) << 3);
            *(half4_t*)(&At[u]) = h;
        }
#pragma unroll
        for (int i = 0; i < 4; i++) {
            int idx = i * 256 + tid;
            int r = idx >> 3, sl = idx & 7;
            int u = (r * 64 + sl * 8) ^ ((r & 7) << 3);
            *(uint4*)(&Bt[u]) = *(const uint4*)(W1t + (size_t)r * IND + kc + sl * 8);
        }
        __syncthreads();
#pragma unroll
        for (int kk = 0; kk < 2; kk++) {
            const int kc2 = kk * 32;
            half8_t af[2];
#pragma unroll
            for (int mt = 0; mt < 2; mt++) {
                int rloc = wid * 32 + mt * 16 + l15;
                int u = (rloc * 64 + kc2 + l4 * 8) ^ ((rloc & 7) << 3);
                af[mt] = *(half8_t*)(&At[u]);
            }
#pragma unroll
            for (int nt = 0; nt < 8; nt++) {
                int cloc = nt * 16 + l15;
                int u = (cloc * 64 + kc2 + l4 * 8) ^ ((cloc & 7) << 3);
                half8_t bf = *(half8_t*)(&Bt[u]);
                acc[0][nt] = __builtin_amdgcn_mfma_f32_16x16x32_f16(af[0], bf, acc[0][nt], 0, 0, 0);
                acc[1][nt] = __builtin_amdgcn_mfma_f32_16x16x32_f16(af[1], bf, acc[1][nt], 0, 0, 0);
            }
        }
        __syncthreads();   // after last iter: At/Bt reads drained -> safe to reuse for H1s
    }

    _Float16* H1w = smem + wid * (32 * 128);
#pragma unroll
    for (int mt = 0; mt < 2; mt++)
#pragma unroll
        for (int nt = 0; nt < 8; nt++)
#pragma unroll
            for (int r = 0; r < 4; r++) {
                int rloc = mt * 16 + l4 * 4 + r;
                int col  = nt * 16 + l15;
                float v = acc[mt][nt][r];
                v = v > 0.f ? v : 0.f;
                int u = (rloc * 128 + col) ^ ((rloc & 7) << 3);
                H1w[u] = (_Float16)v;
            }
    // wave-private strip: lgkmcnt dependency ordering, no barrier needed

    f32x4 acc2[2][4];
#pragma unroll
    for (int mt = 0; mt < 2; mt++)
#pragma unroll
        for (int nt = 0; nt < 4; nt++) acc2[mt][nt] = (f32x4)0.f;

#pragma unroll
    for (int kk = 0; kk < 4; kk++) {
        const int kc = kk * 32;
        half8_t a2[2];
#pragma unroll
        for (int mt = 0; mt < 2; mt++) {
            int rloc = mt * 16 + l15;
            int u = (rloc * 128 + kc + l4 * 8) ^ ((rloc & 7) << 3);
            a2[mt] = *(half8_t*)(&H1w[u]);
        }
#pragma unroll
        for (int nt = 0; nt < 4; nt++) {
            int c = nt * 16 + l15;
            int u = (c * 128 + kc + l4 * 8) ^ ((c & 7) << 3);
            half8_t b2 = *(half8_t*)(&W2s[u]);
            acc2[0][nt] = __builtin_amdgcn_mfma_f32_16x16x32_f16(a2[0], b2, acc2[0][nt], 0, 0, 0);
            acc2[1][nt] = __builtin_amdgcn_mfma_f32_16x16x32_f16(a2[1], b2, acc2[1][nt], 0, 0, 0);
        }
    }
#pragma unroll
    for (int mt = 0; mt < 2; mt++)
#pragma unroll
        for (int nt = 0; nt < 4; nt++)
#pragma unroll
            for (int r = 0; r < 4; r++) {
                int grow = brow + wid * 32 + mt * 16 + l4 * 4 + r;
                if (grow < NN) H2[(size_t)grow * OUTD + nt * 16 + l15] = (_Float16)acc2[mt][nt][r];
            }
}

// ---------------- fat kernel 1: part (blocks 0..NB-1) || gemm tiles 0..GH1-1 ----------------
// part payload: ld(7b)<<25 | src(17b)<<8 | q8 weight; cursors in LDS
__global__ __launch_bounds__(256) void partgemm_k(const int* __restrict__ src,
                                                  const int* __restrict__ dst,
                                                  const float* __restrict__ ew,
                                                  const int* __restrict__ offsets,
                                                  unsigned* __restrict__ edata, int nE, int CH,
                                                  const float* __restrict__ F,
                                                  const _Float16* __restrict__ W1t,
                                                  const _Float16* __restrict__ W2t,
                                                  _Float16* __restrict__ H2) {
    __shared__ _Float16 smem[128 * 64 * 2];
    __shared__ _Float16 W2s[64 * 128];
    const int tid = threadIdx.x;

    if (blockIdx.x < NB) {
        int* cur = (int*)smem;    // 3128 B of the 32 KB
        const int j = blockIdx.x;
        for (int b = tid; b < NBUCK; b += 256) cur[b] = offsets[b * NB + j];
        __syncthreads();
        int lo = j * CH, hi = min(lo + CH, nE);
        for (int e = lo + tid; e < hi; e += 256) {
            int d = dst[e];
            int b = d >> 7;
            int pos = atomicAdd(&cur[b], 1);
            int q = (int)(ew[e] * 255.f + 0.5f);
            if (q > 255) q = 255;
            edata[pos] = ((unsigned)(d & 127) << 25) | ((unsigned)src[e] << 8) | (unsigned)q;
        }
        return;
    }
    gemm_tile(blockIdx.x - NB, F, W1t, W2t, H2, smem, W2s, tid);
}

// ---------------- fat kernel 2: sort (blocks 0..NBUCK-1) || gemm tiles GH1..781 ----------------
// epack: src(17b)<<8 | q8 weight
__global__ __launch_bounds__(256) void sortgemm_k(const unsigned* __restrict__ edata,
                                                  const int* __restrict__ bucketStart,
                                                  unsigned* __restrict__ epack,
                                                  int* __restrict__ rowStart,
                                                  const float* __restrict__ F,
                                                  const _Float16* __restrict__ W1t,
                                                  const _Float16* __restrict__ W2t,
                                                  _Float16* __restrict__ H2) {
    __shared__ _Float16 smem[128 * 64 * 2];
    __shared__ _Float16 W2s[64 * 128];
    const int tid = threadIdx.x;

    if (blockIdx.x < NBUCK) {
        int* bins = (int*)smem;
        int* s    = bins + 128;
        int* cur  = bins + 256;
        const int b = blockIdx.x;
        if (tid < 128) bins[tid] = 0;
        __syncthreads();
        const int beg = bucketStart[b], end = bucketStart[b + 1];
        for (int e = beg + tid; e < end; e += 256)
            atomicAdd(&bins[edata[e] >> 25], 1);
        __syncthreads();
        if (tid < 128) s[tid] = bins[tid];
        __syncthreads();
        for (int off = 1; off < 128; off <<= 1) {
            int x = 0;
            if (tid < 128 && tid >= off) x = s[tid - off];
            __syncthreads();
            if (tid < 128) s[tid] += x;
            __syncthreads();
        }
        if (tid < 128) {
            int excl = beg + s[tid] - bins[tid];
            cur[tid] = excl;
            rowStart[b * 128 + tid] = excl;   // rowStart[NN] lands correctly (trailing bins are 0)
        }
        __syncthreads();
        for (int e = beg + tid; e < end; e += 256) {
            unsigned r = edata[e];
            int ld = r >> 25;
            int pos = atomicAdd(&cur[ld], 1);
            epack[pos] = r & 0x1FFFFFFu;
        }
        return;
    }
    gemm_tile(blockIdx.x - NBUCK + GH1, F, W1t, W2t, H2, smem, W2s, tid);
}

// ---------------- pull propagate: wave per dst, SCALARIZED edge stream ----------------
template <bool LAST>
__global__ __launch_bounds__(256) void pull_k(const _Float16* __restrict__ H,
                                              const unsigned* __restrict__ ep,
                                              const int* __restrict__ rowStart,
                                              _Float16* __restrict__ Zh,
                                              float* __restrict__ Zf) {
    int wv = (int)((blockIdx.x * (long)blockDim.x + threadIdx.x) >> 6);
    const int row = __builtin_amdgcn_readfirstlane(wv);   // provably uniform -> SGPR
    const int lane = threadIdx.x & 63;
    if (row >= NN) return;
    const int beg = rowStart[row];     // s_load
    const int end = rowStart[row + 1]; // s_load
    float acc = 0.f;
    int i = beg;
    for (; i + 8 <= end; i += 8) {
        unsigned u0 = ep[i],     u1 = ep[i + 1], u2 = ep[i + 2], u3 = ep[i + 3];
        unsigned u4 = ep[i + 4], u5 = ep[i + 5], u6 = ep[i + 6], u7 = ep[i + 7];
        float h0 = (float)H[(size_t)(u0 >> 8) * OUTD + lane];
        float h1 = (float)H[(size_t)(u1 >> 8) * OUTD + lane];
        float h2 = (float)H[(size_t)(u2 >> 8) * OUTD + lane];
        float h3 = (float)H[(size_t)(u3 >> 8) * OUTD + lane];
        float h4 = (float)H[(size_t)(u4 >> 8) * OUTD + lane];
        float h5 = (float)H[(size_t)(u5 >> 8) * OUTD + lane];
        float h6 = (float)H[(size_t)(u6 >> 8) * OUTD + lane];
        float h7 = (float)H[(size_t)(u7 >> 8) * OUTD + lane];
        acc += (float)(int)(u0 & 255u) * h0;
        acc += (float)(int)(u1 & 255u) * h1;
        acc += (float)(int)(u2 & 255u) * h2;
        acc += (float)(int)(u3 & 255u) * h3;
        acc += (float)(int)(u4 & 255u) * h4;
        acc += (float)(int)(u5 & 255u) * h5;
        acc += (float)(int)(u6 & 255u) * h6;
        acc += (float)(int)(u7 & 255u) * h7;
    }
    for (; i + 4 <= end; i += 4) {
        unsigned u0 = ep[i], u1 = ep[i + 1], u2 = ep[i + 2], u3 = ep[i + 3];
        float h0 = (float)H[(size_t)(u0 >> 8) * OUTD + lane];
        float h1 = (float)H[(size_t)(u1 >> 8) * OUTD + lane];
        float h2 = (float)H[(size_t)(u2 >> 8) * OUTD + lane];
        float h3 = (float)H[(size_t)(u3 >> 8) * OUTD + lane];
        acc += (float)(int)(u0 & 255u) * h0;
        acc += (float)(int)(u1 & 255u) * h1;
        acc += (float)(int)(u2 & 255u) * h2;
        acc += (float)(int)(u3 & 255u) * h3;
    }
    for (; i < end; i++) {
        unsigned u = ep[i];
        acc += (float)(int)(u & 255u) * (float)H[(size_t)(u >> 8) * OUTD + lane];
    }
    acc *= (1.f / 255.f);
    if (LAST) Zf[(size_t)row * OUTD + lane] = acc;
    else      Zh[(size_t)row * OUTD + lane] = (_Float16)acc;
}

extern "C" void kernel_launch(void* const* d_in, const int* in_sizes, int n_in,
                              void* d_out, int out_size, void* d_ws, size_t ws_size,
                              hipStream_t stream) {
    const float* F   = (const float*)d_in[0];
    const float* W1  = (const float*)d_in[1];
    const float* W2  = (const float*)d_in[2];
    const float* ew  = (const float*)d_in[3];
    const int*   src = (const int*)d_in[4];
    const int*   dst = (const int*)d_in[5];
    float* out = (float*)d_out;
    const int nE = in_sizes[3];

    // ---- workspace layout ----
    char* p = (char*)d_ws;
    _Float16*  h2        = (_Float16*)p;  p += (size_t)NN * OUTD * sizeof(_Float16);   // 12.8 MB
    _Float16*  z1        = (_Float16*)p;  p += (size_t)NN * OUTD * sizeof(_Float16);   // 12.8 MB
    _Float16*  W1t       = (_Float16*)p;  p += (size_t)HID * IND * sizeof(_Float16);
    _Float16*  W2t       = (_Float16*)p;  p += (size_t)OUTD * HID * sizeof(_Float16);
    int*       counts    = (int*)p;       p += (size_t)NBUCK * NB * sizeof(int);       // 800 KB
    int*       bsum      = (int*)p;       p += (size_t)NBUCK * sizeof(int);
    int*       bucketStart=(int*)p;       p += (size_t)(NBUCK + 16) * sizeof(int);
    int*       rowStart  = (int*)p;       p += (size_t)(NN + 160) * sizeof(int);       // 400 KB
    unsigned*  edata     = (unsigned*)p;  p += (size_t)nE * sizeof(unsigned);          // 12.8 MB
    unsigned*  epack     = (unsigned*)p;  p += (size_t)nE * sizeof(unsigned);          // 12.8 MB

    const int CH = (nE + NB - 1) / NB;   // 12500

    // ---- partition chain (count||prep fused; no global atomics anywhere) ----
    countprep_k<<<NB + NPREP, 1024, 0, stream>>>(dst, counts, nE, CH, W1, W2, W1t, W2t);
    bsum_k<<<NBUCK, 256, 0, stream>>>(counts, bsum);
    scan_top_k<<<1, 1024, 0, stream>>>(bsum, bucketStart, NBUCK);
    boff_k<<<NBUCK, 256, 0, stream>>>(counts, bucketStart);

    // ---- part || gemm[0..391], then sort || gemm[392..781] ----
    partgemm_k<<<NB + GH1, 256, 0, stream>>>(src, dst, ew, counts, edata, nE, CH,
                                             F, W1t, W2t, h2);
    sortgemm_k<<<NBUCK + GH2, 256, 0, stream>>>(edata, bucketStart, epack, rowStart,
                                                F, W1t, W2t, h2);

    // ---- 2x pull-propagate (f16 gathers, scalar edge stream) ----
    int blocks = (int)(((long)NN * 64 + 255) / 256);
    pull_k<false><<<blocks, 256, 0, stream>>>(h2, epack, rowStart, z1, nullptr);
    pull_k<true><<<blocks, 256, 0, stream>>>(z1, epack, rowStart, nullptr, out);
}

// Round 13
// 264.772 us; speedup vs baseline: 1.0282x; 1.0282x over previous
//
#include <hip/hip_runtime.h>

#define NN    100000
#define IND   512
#define HID   128
#define OUTD  64
#define NBUCK 782          // ceil(NN/128); bucket = dst >> 7
#define NB    256          // partition chunks
#define NGEMM 782          // (NN+127)/128
#define NPREP 64           // prep blocks appended to count launch

typedef _Float16 half8_t __attribute__((ext_vector_type(8)));
typedef _Float16 half4_t __attribute__((ext_vector_type(4)));
typedef float f32x4 __attribute__((ext_vector_type(4)));

// ---------------- count (blocks 0..NB-1) + prep (blocks NB..NB+NPREP-1) ----------------
__global__ __launch_bounds__(1024) void countprep_k(const int* __restrict__ dst,
                                                    int* __restrict__ counts, int nE, int CH,
                                                    const float* __restrict__ W1,
                                                    const float* __restrict__ W2,
                                                    _Float16* __restrict__ W1t,
                                                    _Float16* __restrict__ W2t) {
    __shared__ int bins[NBUCK];
    const int bid = blockIdx.x, tid = threadIdx.x;
    if (bid >= NB) {   // prep: W1t[c][k] = (f16)W1[k][c], W2t[c][k] = (f16)W2[k][c]
        int idx = (bid - NB) * 1024 + tid;
        if (idx < IND * HID) { int c = idx >> 9, k = idx & 511; W1t[idx] = (_Float16)W1[k * HID + c]; }
        if (idx < HID * OUTD) { int c = idx >> 7, k = idx & 127; W2t[idx] = (_Float16)W2[k * OUTD + c]; }
        return;
    }
    for (int b = tid; b < NBUCK; b += 1024) bins[b] = 0;
    __syncthreads();
    int lo = bid * CH, hi = min(lo + CH, nE);
    for (int e = lo + tid; e < hi; e += 1024) atomicAdd(&bins[dst[e] >> 7], 1);
    __syncthreads();
    for (int b = tid; b < NBUCK; b += 1024) counts[b * NB + bid] = bins[b];
}

__global__ __launch_bounds__(256) void bsum_k(const int* __restrict__ counts,
                                              int* __restrict__ bsum) {
    __shared__ int s[256];
    const int b = blockIdx.x, t = threadIdx.x;
    s[t] = counts[b * NB + t];
    __syncthreads();
    for (int off = 128; off > 0; off >>= 1) {
        if (t < off) s[t] += s[t + off];
        __syncthreads();
    }
    if (t == 0) bsum[b] = s[0];
}

__global__ __launch_bounds__(1024) void scan_top_k(const int* __restrict__ bsum,
                                                   int* __restrict__ bucketStart, int n) {
    __shared__ int s[1024];
    const int t = threadIdx.x;
    int v = (t < n) ? bsum[t] : 0;
    s[t] = v;
    __syncthreads();
    for (int off = 1; off < 1024; off <<= 1) {
        int x = (t >= off) ? s[t - off] : 0;
        __syncthreads();
        s[t] += x;
        __syncthreads();
    }
    if (t < n) bucketStart[t] = s[t] - v;
    if (t == n - 1) bucketStart[n] = s[t];
}

__global__ __launch_bounds__(256) void boff_k(int* __restrict__ counts,
                                              const int* __restrict__ bucketStart) {
    __shared__ int s[256];
    const int b = blockIdx.x, t = threadIdx.x;
    int v = counts[b * NB + t];
    s[t] = v;
    __syncthreads();
    for (int off = 1; off < 256; off <<= 1) {
        int x = (t >= off) ? s[t - off] : 0;
        __syncthreads();
        s[t] += x;
        __syncthreads();
    }
    counts[b * NB + t] = bucketStart[b] + s[t] - v;
}

// scatter edges into bucket-contiguous edata (single uint payload), cursors in LDS
// payload: ld(7b)<<25 | src(17b)<<8 | q8 weight
__global__ __launch_bounds__(1024) void part_k(const int* __restrict__ src,
                                               const int* __restrict__ dst,
                                               const float* __restrict__ ew,
                                               const int* __restrict__ offsets,
                                               unsigned* __restrict__ edata, int nE, int CH) {
    __shared__ int cur[NBUCK];
    const int j = blockIdx.x, tid = threadIdx.x;
    for (int b = tid; b < NBUCK; b += 1024) cur[b] = offsets[b * NB + j];
    __syncthreads();
    int lo = j * CH, hi = min(lo + CH, nE);
    for (int e = lo + tid; e < hi; e += 1024) {
        int d = dst[e];
        int b = d >> 7;
        int pos = atomicAdd(&cur[b], 1);
        int q = (int)(ew[e] * 255.f + 0.5f);
        if (q > 255) q = 255;
        edata[pos] = ((unsigned)(d & 127) << 25) | ((unsigned)src[e] << 8) | (unsigned)q;
    }
}

// ---------------- fat kernel: sort (blocks 0..NBUCK-1) || fused gemm (NBUCK..) ----------------
__global__ __launch_bounds__(256) void gemmsort_k(const float* __restrict__ F,
                                                  const _Float16* __restrict__ W1t,
                                                  const _Float16* __restrict__ W2t,
                                                  _Float16* __restrict__ H2,
                                                  const unsigned* __restrict__ edata,
                                                  const int* __restrict__ bucketStart,
                                                  unsigned* __restrict__ epack,
                                                  int* __restrict__ rowStart) {
    __shared__ _Float16 smem[128 * 64 * 2];   // gemm: At|Bt then H1s; sort: bins|s|cur (ints)
    __shared__ _Float16 W2s[64 * 128];
    const int tid = threadIdx.x;

    if (blockIdx.x < NBUCK) {
        // ---------- per-bucket counting sort ----------
        int* bins = (int*)smem;
        int* s    = bins + 128;
        int* cur  = bins + 256;
        const int b = blockIdx.x;
        if (tid < 128) bins[tid] = 0;
        __syncthreads();
        const int beg = bucketStart[b], end = bucketStart[b + 1];
        for (int e = beg + tid; e < end; e += 256)
            atomicAdd(&bins[edata[e] >> 25], 1);
        __syncthreads();
        if (tid < 128) s[tid] = bins[tid];
        __syncthreads();
        for (int off = 1; off < 128; off <<= 1) {
            int x = 0;
            if (tid < 128 && tid >= off) x = s[tid - off];
            __syncthreads();
            if (tid < 128) s[tid] += x;
            __syncthreads();
        }
        if (tid < 128) {
            int excl = beg + s[tid] - bins[tid];
            cur[tid] = excl;
            rowStart[b * 128 + tid] = excl;
        }
        __syncthreads();
        for (int e = beg + tid; e < end; e += 256) {
            unsigned r = edata[e];
            int ld = r >> 25;
            int pos = atomicAdd(&cur[ld], 1);
            epack[pos] = r & 0x1FFFFFFu;
        }
        return;
    }

    // ---------- fused GEMM: H2 = relu(F @ W1) @ W2 ----------
    _Float16* At = smem;
    _Float16* Bt = smem + 128 * 64;
    const int wid  = tid >> 6;
    const int lane = tid & 63;
    const int l15  = lane & 15;
    const int l4   = lane >> 4;
    const int brow = (blockIdx.x - NBUCK) * 128;

#pragma unroll
    for (int i = 0; i < 4; i++) {
        int idx = i * 256 + tid;
        int r = idx >> 4, sl = idx & 15;
        int u = (r * 128 + sl * 8) ^ ((r & 7) << 3);
        *(uint4*)(&W2s[u]) = *(const uint4*)(W2t + r * 128 + sl * 8);
    }

    f32x4 acc[2][8];
#pragma unroll
    for (int mt = 0; mt < 2; mt++)
#pragma unroll
        for (int nt = 0; nt < 8; nt++) acc[mt][nt] = (f32x4)0.f;

    for (int chunk = 0; chunk < 8; chunk++) {
        const int kc = chunk * 64;
#pragma unroll
        for (int i = 0; i < 8; i++) {
            int idx = i * 256 + tid;
            int r = idx >> 4, c4 = idx & 15;
            int gr = brow + r; if (gr >= NN) gr = NN - 1;
            float4 v = *(const float4*)(F + (size_t)gr * IND + kc + c4 * 4);
            half4_t h; h.x = (_Float16)v.x; h.y = (_Float16)v.y; h.z = (_Float16)v.z; h.w = (_Float16)v.w;
            int u = (r * 64 + c4 * 4) ^ ((r & 7) << 3);
            *(half4_t*)(&At[u]) = h;
        }
#pragma unroll
        for (int i = 0; i < 4; i++) {
            int idx = i * 256 + tid;
            int r = idx >> 3, sl = idx & 7;
            int u = (r * 64 + sl * 8) ^ ((r & 7) << 3);
            *(uint4*)(&Bt[u]) = *(const uint4*)(W1t + (size_t)r * IND + kc + sl * 8);
        }
        __syncthreads();
#pragma unroll
        for (int kk = 0; kk < 2; kk++) {
            const int kc2 = kk * 32;
            half8_t af[2];
#pragma unroll
            for (int mt = 0; mt < 2; mt++) {
                int rloc = wid * 32 + mt * 16 + l15;
                int u = (rloc * 64 + kc2 + l4 * 8) ^ ((rloc & 7) << 3);
                af[mt] = *(half8_t*)(&At[u]);
            }
#pragma unroll
            for (int nt = 0; nt < 8; nt++) {
                int cloc = nt * 16 + l15;
                int u = (cloc * 64 + kc2 + l4 * 8) ^ ((cloc & 7) << 3);
                half8_t bf = *(half8_t*)(&Bt[u]);
                acc[0][nt] = __builtin_amdgcn_mfma_f32_16x16x32_f16(af[0], bf, acc[0][nt], 0, 0, 0);
                acc[1][nt] = __builtin_amdgcn_mfma_f32_16x16x32_f16(af[1], bf, acc[1][nt], 0, 0, 0);
            }
        }
        __syncthreads();   // after last iter: At/Bt reads drained -> safe to reuse for H1s
    }

    _Float16* H1w = smem + wid * (32 * 128);
#pragma unroll
    for (int mt = 0; mt < 2; mt++)
#pragma unroll
        for (int nt = 0; nt < 8; nt++)
#pragma unroll
            for (int r = 0; r < 4; r++) {
                int rloc = mt * 16 + l4 * 4 + r;
                int col  = nt * 16 + l15;
                float v = acc[mt][nt][r];
                v = v > 0.f ? v : 0.f;
                int u = (rloc * 128 + col) ^ ((rloc & 7) << 3);
                H1w[u] = (_Float16)v;
            }
    // wave-private strip: lgkmcnt dependency ordering, no barrier needed

    f32x4 acc2[2][4];
#pragma unroll
    for (int mt = 0; mt < 2; mt++)
#pragma unroll
        for (int nt = 0; nt < 4; nt++) acc2[mt][nt] = (f32x4)0.f;

#pragma unroll
    for (int kk = 0; kk < 4; kk++) {
        const int kc = kk * 32;
        half8_t a2[2];
#pragma unroll
        for (int mt = 0; mt < 2; mt++) {
            int rloc = mt * 16 + l15;
            int u = (rloc * 128 + kc + l4 * 8) ^ ((rloc & 7) << 3);
            a2[mt] = *(half8_t*)(&H1w[u]);
        }
#pragma unroll
        for (int nt = 0; nt < 4; nt++) {
            int c = nt * 16 + l15;
            int u = (c * 128 + kc + l4 * 8) ^ ((c & 7) << 3);
            half8_t b2 = *(half8_t*)(&W2s[u]);
            acc2[0][nt] = __builtin_amdgcn_mfma_f32_16x16x32_f16(a2[0], b2, acc2[0][nt], 0, 0, 0);
            acc2[1][nt] = __builtin_amdgcn_mfma_f32_16x16x32_f16(a2[1], b2, acc2[1][nt], 0, 0, 0);
        }
    }
#pragma unroll
    for (int mt = 0; mt < 2; mt++)
#pragma unroll
        for (int nt = 0; nt < 4; nt++)
#pragma unroll
            for (int r = 0; r < 4; r++) {
                int grow = brow + wid * 32 + mt * 16 + l4 * 4 + r;
                if (grow < NN) H2[(size_t)grow * OUTD + nt * 16 + l15] = (_Float16)acc2[mt][nt][r];
            }
}

// ---------------- pull propagate: QUARTER-wave per edge ----------------
// 16 lanes per edge; lane reads f16x4 (8 B) -> 1 gather instruction covers 4 edges
// (4x fewer VMEM issues). Edge stream stays scalar (uniform ep[i..i+3] s_loads,
// per-quarter select). Cross-quarter combine: 2x shfl_xor.
template <bool LAST>
__global__ __launch_bounds__(256) void pull_k(const _Float16* __restrict__ H,
                                              const unsigned* __restrict__ ep,
                                              const int* __restrict__ rowStart,
                                              _Float16* __restrict__ Zh,
                                              float* __restrict__ Zf) {
    int wv = (int)((blockIdx.x * (long)blockDim.x + threadIdx.x) >> 6);
    const int row = __builtin_amdgcn_readfirstlane(wv);   // provably uniform -> SGPR
    const int lane = threadIdx.x & 63;
    const int qw = lane >> 4;      // quarter 0..3 = which edge of the group
    const int li = lane & 15;      // feature group: features li*4 .. li*4+3
    if (row >= NN) return;
    const int beg = rowStart[row];     // s_load
    const int end = rowStart[row + 1]; // s_load
    float a0 = 0.f, a1 = 0.f, a2 = 0.f, a3 = 0.f;
    int i = beg;
    for (; i + 8 <= end; i += 8) {     // 2 gathers in flight per iter
        unsigned e0 = ep[i],     e1 = ep[i + 1], e2 = ep[i + 2], e3 = ep[i + 3];
        unsigned e4 = ep[i + 4], e5 = ep[i + 5], e6 = ep[i + 6], e7 = ep[i + 7];
        unsigned ua = qw == 0 ? e0 : qw == 1 ? e1 : qw == 2 ? e2 : e3;
        unsigned ub = qw == 0 ? e4 : qw == 1 ? e5 : qw == 2 ? e6 : e7;
        half4_t va = *(const half4_t*)(H + (size_t)(ua >> 8) * OUTD + li * 4);
        half4_t vb = *(const half4_t*)(H + (size_t)(ub >> 8) * OUTD + li * 4);
        float wa = (float)(int)(ua & 255u);
        float wb = (float)(int)(ub & 255u);
        a0 += wa * (float)va.x; a1 += wa * (float)va.y;
        a2 += wa * (float)va.z; a3 += wa * (float)va.w;
        a0 += wb * (float)vb.x; a1 += wb * (float)vb.y;
        a2 += wb * (float)vb.z; a3 += wb * (float)vb.w;
    }
    for (; i + 4 <= end; i += 4) {
        unsigned e0 = ep[i], e1 = ep[i + 1], e2 = ep[i + 2], e3 = ep[i + 3];
        unsigned u = qw == 0 ? e0 : qw == 1 ? e1 : qw == 2 ? e2 : e3;
        half4_t v = *(const half4_t*)(H + (size_t)(u >> 8) * OUTD + li * 4);
        float w = (float)(int)(u & 255u);
        a0 += w * (float)v.x; a1 += w * (float)v.y;
        a2 += w * (float)v.z; a3 += w * (float)v.w;
    }
    for (; i < end; i++) {             // tail <=3 edges: quarter 0 only
        unsigned u = ep[i];
        if (qw == 0) {
            half4_t v = *(const half4_t*)(H + (size_t)(u >> 8) * OUTD + li * 4);
            float w = (float)(int)(u & 255u);
            a0 += w * (float)v.x; a1 += w * (float)v.y;
            a2 += w * (float)v.z; a3 += w * (float)v.w;
        }
    }
    // combine quarters (feature group li lives at lanes li, li+16, li+32, li+48)
    a0 += __shfl_xor(a0, 16, 64); a0 += __shfl_xor(a0, 32, 64);
    a1 += __shfl_xor(a1, 16, 64); a1 += __shfl_xor(a1, 32, 64);
    a2 += __shfl_xor(a2, 16, 64); a2 += __shfl_xor(a2, 32, 64);
    a3 += __shfl_xor(a3, 16, 64); a3 += __shfl_xor(a3, 32, 64);
    if (qw == 0) {
        const float sc = 1.f / 255.f;
        a0 *= sc; a1 *= sc; a2 *= sc; a3 *= sc;
        if (LAST) {
            *(float4*)(Zf + (size_t)row * OUTD + li * 4) = make_float4(a0, a1, a2, a3);
        } else {
            half4_t o; o.x = (_Float16)a0; o.y = (_Float16)a1;
            o.z = (_Float16)a2; o.w = (_Float16)a3;
            *(half4_t*)(Zh + (size_t)row * OUTD + li * 4) = o;
        }
    }
}

extern "C" void kernel_launch(void* const* d_in, const int* in_sizes, int n_in,
                              void* d_out, int out_size, void* d_ws, size_t ws_size,
                              hipStream_t stream) {
    const float* F   = (const float*)d_in[0];
    const float* W1  = (const float*)d_in[1];
    const float* W2  = (const float*)d_in[2];
    const float* ew  = (const float*)d_in[3];
    const int*   src = (const int*)d_in[4];
    const int*   dst = (const int*)d_in[5];
    float* out = (float*)d_out;
    const int nE = in_sizes[3];

    // ---- workspace layout ----
    char* p = (char*)d_ws;
    _Float16*  h2        = (_Float16*)p;  p += (size_t)NN * OUTD * sizeof(_Float16);   // 12.8 MB
    _Float16*  z1        = (_Float16*)p;  p += (size_t)NN * OUTD * sizeof(_Float16);   // 12.8 MB
    _Float16*  W1t       = (_Float16*)p;  p += (size_t)HID * IND * sizeof(_Float16);
    _Float16*  W2t       = (_Float16*)p;  p += (size_t)OUTD * HID * sizeof(_Float16);
    int*       counts    = (int*)p;       p += (size_t)NBUCK * NB * sizeof(int);       // 800 KB
    int*       bsum      = (int*)p;       p += (size_t)NBUCK * sizeof(int);
    int*       bucketStart=(int*)p;       p += (size_t)(NBUCK + 16) * sizeof(int);
    int*       rowStart  = (int*)p;       p += (size_t)(NN + 160) * sizeof(int);       // 400 KB
    unsigned*  edata     = (unsigned*)p;  p += (size_t)nE * sizeof(unsigned);          // 12.8 MB
    unsigned*  epack     = (unsigned*)p;  p += (size_t)nE * sizeof(unsigned);          // 12.8 MB

    const int CH = (nE + NB - 1) / NB;   // 12500

    // ---- partition chain (count||prep fused; no global atomics anywhere) ----
    countprep_k<<<NB + NPREP, 1024, 0, stream>>>(dst, counts, nE, CH, W1, W2, W1t, W2t);
    bsum_k<<<NBUCK, 256, 0, stream>>>(counts, bsum);
    scan_top_k<<<1, 1024, 0, stream>>>(bsum, bucketStart, NBUCK);
    boff_k<<<NBUCK, 256, 0, stream>>>(counts, bucketStart);
    part_k<<<NB, 1024, 0, stream>>>(src, dst, ew, counts, edata, nE, CH);

    // ---- sort || fused gemm in one launch ----
    gemmsort_k<<<NBUCK + NGEMM, 256, 0, stream>>>(F, W1t, W2t, h2,
                                                  edata, bucketStart, epack, rowStart);

    // ---- 2x pull-propagate (quarter-wave f16x4 gathers, scalar edge stream) ----
    int blocks = (int)(((long)NN * 64 + 255) / 256);
    pull_k<false><<<blocks, 256, 0, stream>>>(h2, epack, rowStart, z1, nullptr);
    pull_k<true><<<blocks, 256, 0, stream>>>(z1, epack, rowStart, nullptr, out);
}

// Round 14
// 248.385 us; speedup vs baseline: 1.0960x; 1.0660x over previous
//
#include <hip/hip_runtime.h>

#define NN    100000
#define IND   512
#define HID   128
#define OUTD  64
#define NBUCK 782          // ceil(NN/128); bucket = dst >> 7
#define NB    256          // partition chunks
#define NGEMM 782          // (NN+127)/128
#define NPREP 64           // prep blocks appended to count launch

typedef _Float16 half8_t __attribute__((ext_vector_type(8)));
typedef _Float16 half4_t __attribute__((ext_vector_type(4)));
typedef float f32x4 __attribute__((ext_vector_type(4)));

// ---------------- count (blocks 0..NB-1) + prep (blocks NB..NB+NPREP-1) ----------------
// dst read vectorized int4 (4 edges/thread/iter).
__global__ __launch_bounds__(1024) void countprep_k(const int* __restrict__ dst,
                                                    int* __restrict__ counts, int nE, int CH,
                                                    const float* __restrict__ W1,
                                                    const float* __restrict__ W2,
                                                    _Float16* __restrict__ W1t,
                                                    _Float16* __restrict__ W2t) {
    __shared__ int bins[NBUCK];
    const int bid = blockIdx.x, tid = threadIdx.x;
    if (bid >= NB) {   // prep: W1t[c][k] = (f16)W1[k][c], W2t[c][k] = (f16)W2[k][c]
        int idx = (bid - NB) * 1024 + tid;
        if (idx < IND * HID) { int c = idx >> 9, k = idx & 511; W1t[idx] = (_Float16)W1[k * HID + c]; }
        if (idx < HID * OUTD) { int c = idx >> 7, k = idx & 127; W2t[idx] = (_Float16)W2[k * OUTD + c]; }
        return;
    }
    for (int b = tid; b < NBUCK; b += 1024) bins[b] = 0;
    __syncthreads();
    const int lo = bid * CH, hi = min(lo + CH, nE);
    if (((lo | (hi - lo)) & 3) == 0) {          // aligned whole-chunk vector path
        for (int e = lo + tid * 4; e < hi; e += 4096) {
            int4 d = *(const int4*)(dst + e);
            atomicAdd(&bins[d.x >> 7], 1);
            atomicAdd(&bins[d.y >> 7], 1);
            atomicAdd(&bins[d.z >> 7], 1);
            atomicAdd(&bins[d.w >> 7], 1);
        }
    } else {
        for (int e = lo + tid; e < hi; e += 1024) atomicAdd(&bins[dst[e] >> 7], 1);
    }
    __syncthreads();
    for (int b = tid; b < NBUCK; b += 1024) counts[b * NB + bid] = bins[b];
}

__global__ __launch_bounds__(256) void bsum_k(const int* __restrict__ counts,
                                              int* __restrict__ bsum) {
    __shared__ int s[256];
    const int b = blockIdx.x, t = threadIdx.x;
    s[t] = counts[b * NB + t];
    __syncthreads();
    for (int off = 128; off > 0; off >>= 1) {
        if (t < off) s[t] += s[t + off];
        __syncthreads();
    }
    if (t == 0) bsum[b] = s[0];
}

__global__ __launch_bounds__(1024) void scan_top_k(const int* __restrict__ bsum,
                                                   int* __restrict__ bucketStart, int n) {
    __shared__ int s[1024];
    const int t = threadIdx.x;
    int v = (t < n) ? bsum[t] : 0;
    s[t] = v;
    __syncthreads();
    for (int off = 1; off < 1024; off <<= 1) {
        int x = (t >= off) ? s[t - off] : 0;
        __syncthreads();
        s[t] += x;
        __syncthreads();
    }
    if (t < n) bucketStart[t] = s[t] - v;
    if (t == n - 1) bucketStart[n] = s[t];
}

__global__ __launch_bounds__(256) void boff_k(int* __restrict__ counts,
                                              const int* __restrict__ bucketStart) {
    __shared__ int s[256];
    const int b = blockIdx.x, t = threadIdx.x;
    int v = counts[b * NB + t];
    s[t] = v;
    __syncthreads();
    for (int off = 1; off < 256; off <<= 1) {
        int x = (t >= off) ? s[t - off] : 0;
        __syncthreads();
        s[t] += x;
        __syncthreads();
    }
    counts[b * NB + t] = bucketStart[b] + s[t] - v;
}

// scatter edges into bucket-contiguous edata (single uint payload), cursors in LDS
// payload: ld(7b)<<25 | src(17b)<<8 | q8 weight; src/dst/ew reads vectorized int4/float4
__global__ __launch_bounds__(1024) void part_k(const int* __restrict__ src,
                                               const int* __restrict__ dst,
                                               const float* __restrict__ ew,
                                               const int* __restrict__ offsets,
                                               unsigned* __restrict__ edata, int nE, int CH) {
    __shared__ int cur[NBUCK];
    const int j = blockIdx.x, tid = threadIdx.x;
    for (int b = tid; b < NBUCK; b += 1024) cur[b] = offsets[b * NB + j];
    __syncthreads();
    const int lo = j * CH, hi = min(lo + CH, nE);
    if (((lo | (hi - lo)) & 3) == 0) {          // aligned whole-chunk vector path
        for (int e = lo + tid * 4; e < hi; e += 4096) {
            int4   d4 = *(const int4*)(dst + e);
            int4   s4 = *(const int4*)(src + e);
            float4 w4 = *(const float4*)(ew + e);
#pragma unroll
            for (int k = 0; k < 4; k++) {
                int   d = k == 0 ? d4.x : k == 1 ? d4.y : k == 2 ? d4.z : d4.w;
                int   s = k == 0 ? s4.x : k == 1 ? s4.y : k == 2 ? s4.z : s4.w;
                float w = k == 0 ? w4.x : k == 1 ? w4.y : k == 2 ? w4.z : w4.w;
                int pos = atomicAdd(&cur[d >> 7], 1);
                int q = (int)(w * 255.f + 0.5f);
                if (q > 255) q = 255;
                edata[pos] = ((unsigned)(d & 127) << 25) | ((unsigned)s << 8) | (unsigned)q;
            }
        }
    } else {
        for (int e = lo + tid; e < hi; e += 1024) {
            int d = dst[e];
            int pos = atomicAdd(&cur[d >> 7], 1);
            int q = (int)(ew[e] * 255.f + 0.5f);
            if (q > 255) q = 255;
            edata[pos] = ((unsigned)(d & 127) << 25) | ((unsigned)src[e] << 8) | (unsigned)q;
        }
    }
}

// ---------------- fat kernel: sort (blocks 0..NBUCK-1) || fused gemm (NBUCK..) ----------------
__global__ __launch_bounds__(256) void gemmsort_k(const float* __restrict__ F,
                                                  const _Float16* __restrict__ W1t,
                                                  const _Float16* __restrict__ W2t,
                                                  _Float16* __restrict__ H2,
                                                  const unsigned* __restrict__ edata,
                                                  const int* __restrict__ bucketStart,
                                                  unsigned* __restrict__ epack,
                                                  int* __restrict__ rowStart) {
    __shared__ _Float16 smem[128 * 64 * 2];   // gemm: At|Bt then H1s; sort: bins|s|cur (ints)
    __shared__ _Float16 W2s[64 * 128];
    const int tid = threadIdx.x;

    if (blockIdx.x < NBUCK) {
        // ---------- per-bucket counting sort ----------
        int* bins = (int*)smem;
        int* s    = bins + 128;
        int* cur  = bins + 256;
        const int b = blockIdx.x;
        if (tid < 128) bins[tid] = 0;
        __syncthreads();
        const int beg = bucketStart[b], end = bucketStart[b + 1];
        for (int e = beg + tid; e < end; e += 256)
            atomicAdd(&bins[edata[e] >> 25], 1);
        __syncthreads();
        if (tid < 128) s[tid] = bins[tid];
        __syncthreads();
        for (int off = 1; off < 128; off <<= 1) {
            int x = 0;
            if (tid < 128 && tid >= off) x = s[tid - off];
            __syncthreads();
            if (tid < 128) s[tid] += x;
            __syncthreads();
        }
        if (tid < 128) {
            int excl = beg + s[tid] - bins[tid];
            cur[tid] = excl;
            rowStart[b * 128 + tid] = excl;
        }
        __syncthreads();
        for (int e = beg + tid; e < end; e += 256) {
            unsigned r = edata[e];
            int ld = r >> 25;
            int pos = atomicAdd(&cur[ld], 1);
            epack[pos] = r & 0x1FFFFFFu;
        }
        return;
    }

    // ---------- fused GEMM: H2 = relu(F @ W1) @ W2 ----------
    _Float16* At = smem;
    _Float16* Bt = smem + 128 * 64;
    const int wid  = tid >> 6;
    const int lane = tid & 63;
    const int l15  = lane & 15;
    const int l4   = lane >> 4;
    const int brow = (blockIdx.x - NBUCK) * 128;

#pragma unroll
    for (int i = 0; i < 4; i++) {
        int idx = i * 256 + tid;
        int r = idx >> 4, sl = idx & 15;
        int u = (r * 128 + sl * 8) ^ ((r & 7) << 3);
        *(uint4*)(&W2s[u]) = *(const uint4*)(W2t + r * 128 + sl * 8);
    }

    f32x4 acc[2][8];
#pragma unroll
    for (int mt = 0; mt < 2; mt++)
#pragma unroll
        for (int nt = 0; nt < 8; nt++) acc[mt][nt] = (f32x4)0.f;

    for (int chunk = 0; chunk < 8; chunk++) {
        const int kc = chunk * 64;
#pragma unroll
        for (int i = 0; i < 8; i++) {
            int idx = i * 256 + tid;
            int r = idx >> 4, c4 = idx & 15;
            int gr = brow + r; if (gr >= NN) gr = NN - 1;
            float4 v = *(const float4*)(F + (size_t)gr * IND + kc + c4 * 4);
            half4_t h; h.x = (_Float16)v.x; h.y = (_Float16)v.y; h.z = (_Float16)v.z; h.w = (_Float16)v.w;
            int u = (r * 64 + c4 * 4) ^ ((r & 7) << 3);
            *(half4_t*)(&At[u]) = h;
        }
#pragma unroll
        for (int i = 0; i < 4; i++) {
            int idx = i * 256 + tid;
            int r = idx >> 3, sl = idx & 7;
            int u = (r * 64 + sl * 8) ^ ((r & 7) << 3);
            *(uint4*)(&Bt[u]) = *(const uint4*)(W1t + (size_t)r * IND + kc + sl * 8);
        }
        __syncthreads();
#pragma unroll
        for (int kk = 0; kk < 2; kk++) {
            const int kc2 = kk * 32;
            half8_t af[2];
#pragma unroll
            for (int mt = 0; mt < 2; mt++) {
                int rloc = wid * 32 + mt * 16 + l15;
                int u = (rloc * 64 + kc2 + l4 * 8) ^ ((rloc & 7) << 3);
                af[mt] = *(half8_t*)(&At[u]);
            }
#pragma unroll
            for (int nt = 0; nt < 8; nt++) {
                int cloc = nt * 16 + l15;
                int u = (cloc * 64 + kc2 + l4 * 8) ^ ((cloc & 7) << 3);
                half8_t bf = *(half8_t*)(&Bt[u]);
                acc[0][nt] = __builtin_amdgcn_mfma_f32_16x16x32_f16(af[0], bf, acc[0][nt], 0, 0, 0);
                acc[1][nt] = __builtin_amdgcn_mfma_f32_16x16x32_f16(af[1], bf, acc[1][nt], 0, 0, 0);
            }
        }
        __syncthreads();   // after last iter: At/Bt reads drained -> safe to reuse for H1s
    }

    _Float16* H1w = smem + wid * (32 * 128);
#pragma unroll
    for (int mt = 0; mt < 2; mt++)
#pragma unroll
        for (int nt = 0; nt < 8; nt++)
#pragma unroll
            for (int r = 0; r < 4; r++) {
                int rloc = mt * 16 + l4 * 4 + r;
                int col  = nt * 16 + l15;
                float v = acc[mt][nt][r];
                v = v > 0.f ? v : 0.f;
                int u = (rloc * 128 + col) ^ ((rloc & 7) << 3);
                H1w[u] = (_Float16)v;
            }
    // wave-private strip: lgkmcnt dependency ordering, no barrier needed

    f32x4 acc2[2][4];
#pragma unroll
    for (int mt = 0; mt < 2; mt++)
#pragma unroll
        for (int nt = 0; nt < 4; nt++) acc2[mt][nt] = (f32x4)0.f;

#pragma unroll
    for (int kk = 0; kk < 4; kk++) {
        const int kc = kk * 32;
        half8_t a2[2];
#pragma unroll
        for (int mt = 0; mt < 2; mt++) {
            int rloc = mt * 16 + l15;
            int u = (rloc * 128 + kc + l4 * 8) ^ ((rloc & 7) << 3);
            a2[mt] = *(half8_t*)(&H1w[u]);
        }
#pragma unroll
        for (int nt = 0; nt < 4; nt++) {
            int c = nt * 16 + l15;
            int u = (c * 128 + kc + l4 * 8) ^ ((c & 7) << 3);
            half8_t b2 = *(half8_t*)(&W2s[u]);
            acc2[0][nt] = __builtin_amdgcn_mfma_f32_16x16x32_f16(a2[0], b2, acc2[0][nt], 0, 0, 0);
            acc2[1][nt] = __builtin_amdgcn_mfma_f32_16x16x32_f16(a2[1], b2, acc2[1][nt], 0, 0, 0);
        }
    }
#pragma unroll
    for (int mt = 0; mt < 2; mt++)
#pragma unroll
        for (int nt = 0; nt < 4; nt++)
#pragma unroll
            for (int r = 0; r < 4; r++) {
                int grow = brow + wid * 32 + mt * 16 + l4 * 4 + r;
                if (grow < NN) H2[(size_t)grow * OUTD + nt * 16 + l15] = (_Float16)acc2[mt][nt][r];
            }
}

// ---------------- pull propagate: wave per dst, SCALARIZED edge stream (R11) ----------------
template <bool LAST>
__global__ __launch_bounds__(256) void pull_k(const _Float16* __restrict__ H,
                                              const unsigned* __restrict__ ep,
                                              const int* __restrict__ rowStart,
                                              _Float16* __restrict__ Zh,
                                              float* __restrict__ Zf) {
    int wv = (int)((blockIdx.x * (long)blockDim.x + threadIdx.x) >> 6);
    const int row = __builtin_amdgcn_readfirstlane(wv);   // provably uniform -> SGPR
    const int lane = threadIdx.x & 63;
    if (row >= NN) return;
    const int beg = rowStart[row];     // s_load
    const int end = rowStart[row + 1]; // s_load
    float acc = 0.f;
    int i = beg;
    for (; i + 8 <= end; i += 8) {
        unsigned u0 = ep[i],     u1 = ep[i + 1], u2 = ep[i + 2], u3 = ep[i + 3];
        unsigned u4 = ep[i + 4], u5 = ep[i + 5], u6 = ep[i + 6], u7 = ep[i + 7];
        float h0 = (float)H[(size_t)(u0 >> 8) * OUTD + lane];
        float h1 = (float)H[(size_t)(u1 >> 8) * OUTD + lane];
        float h2 = (float)H[(size_t)(u2 >> 8) * OUTD + lane];
        float h3 = (float)H[(size_t)(u3 >> 8) * OUTD + lane];
        float h4 = (float)H[(size_t)(u4 >> 8) * OUTD + lane];
        float h5 = (float)H[(size_t)(u5 >> 8) * OUTD + lane];
        float h6 = (float)H[(size_t)(u6 >> 8) * OUTD + lane];
        float h7 = (float)H[(size_t)(u7 >> 8) * OUTD + lane];
        acc += (float)(int)(u0 & 255u) * h0;
        acc += (float)(int)(u1 & 255u) * h1;
        acc += (float)(int)(u2 & 255u) * h2;
        acc += (float)(int)(u3 & 255u) * h3;
        acc += (float)(int)(u4 & 255u) * h4;
        acc += (float)(int)(u5 & 255u) * h5;
        acc += (float)(int)(u6 & 255u) * h6;
        acc += (float)(int)(u7 & 255u) * h7;
    }
    for (; i + 4 <= end; i += 4) {
        unsigned u0 = ep[i], u1 = ep[i + 1], u2 = ep[i + 2], u3 = ep[i + 3];
        float h0 = (float)H[(size_t)(u0 >> 8) * OUTD + lane];
        float h1 = (float)H[(size_t)(u1 >> 8) * OUTD + lane];
        float h2 = (float)H[(size_t)(u2 >> 8) * OUTD + lane];
        float h3 = (float)H[(size_t)(u3 >> 8) * OUTD + lane];
        acc += (float)(int)(u0 & 255u) * h0;
        acc += (float)(int)(u1 & 255u) * h1;
        acc += (float)(int)(u2 & 255u) * h2;
        acc += (float)(int)(u3 & 255u) * h3;
    }
    for (; i < end; i++) {
        unsigned u = ep[i];
        acc += (float)(int)(u & 255u) * (float)H[(size_t)(u >> 8) * OUTD + lane];
    }
    acc *= (1.f / 255.f);
    if (LAST) Zf[(size_t)row * OUTD + lane] = acc;
    else      Zh[(size_t)row * OUTD + lane] = (_Float16)acc;
}

extern "C" void kernel_launch(void* const* d_in, const int* in_sizes, int n_in,
                              void* d_out, int out_size, void* d_ws, size_t ws_size,
                              hipStream_t stream) {
    const float* F   = (const float*)d_in[0];
    const float* W1  = (const float*)d_in[1];
    const float* W2  = (const float*)d_in[2];
    const float* ew  = (const float*)d_in[3];
    const int*   src = (const int*)d_in[4];
    const int*   dst = (const int*)d_in[5];
    float* out = (float*)d_out;
    const int nE = in_sizes[3];

    // ---- workspace layout ----
    char* p = (char*)d_ws;
    _Float16*  h2        = (_Float16*)p;  p += (size_t)NN * OUTD * sizeof(_Float16);   // 12.8 MB
    _Float16*  z1        = (_Float16*)p;  p += (size_t)NN * OUTD * sizeof(_Float16);   // 12.8 MB
    _Float16*  W1t       = (_Float16*)p;  p += (size_t)HID * IND * sizeof(_Float16);
    _Float16*  W2t       = (_Float16*)p;  p += (size_t)OUTD * HID * sizeof(_Float16);
    int*       counts    = (int*)p;       p += (size_t)NBUCK * NB * sizeof(int);       // 800 KB
    int*       bsum      = (int*)p;       p += (size_t)NBUCK * sizeof(int);
    int*       bucketStart=(int*)p;       p += (size_t)(NBUCK + 16) * sizeof(int);
    int*       rowStart  = (int*)p;       p += (size_t)(NN + 160) * sizeof(int);       // 400 KB
    unsigned*  edata     = (unsigned*)p;  p += (size_t)nE * sizeof(unsigned);          // 12.8 MB
    unsigned*  epack     = (unsigned*)p;  p += (size_t)nE * sizeof(unsigned);          // 12.8 MB

    const int CH = (nE + NB - 1) / NB;   // 12500

    // ---- partition chain (count||prep fused; vectorized loads; no global atomics) ----
    countprep_k<<<NB + NPREP, 1024, 0, stream>>>(dst, counts, nE, CH, W1, W2, W1t, W2t);
    bsum_k<<<NBUCK, 256, 0, stream>>>(counts, bsum);
    scan_top_k<<<1, 1024, 0, stream>>>(bsum, bucketStart, NBUCK);
    boff_k<<<NBUCK, 256, 0, stream>>>(counts, bucketStart);
    part_k<<<NB, 1024, 0, stream>>>(src, dst, ew, counts, edata, nE, CH);

    // ---- sort || fused gemm in one launch ----
    gemmsort_k<<<NBUCK + NGEMM, 256, 0, stream>>>(F, W1t, W2t, h2,
                                                  edata, bucketStart, epack, rowStart);

    // ---- 2x pull-propagate (f16 gathers, scalar edge stream) ----
    int blocks = (int)(((long)NN * 64 + 255) / 256);
    pull_k<false><<<blocks, 256, 0, stream>>>(h2, epack, rowStart, z1, nullptr);
    pull_k<true><<<blocks, 256, 0, stream>>>(z1, epack, rowStart, nullptr, out);
}